// Round 7
// baseline (62.695 us; speedup 1.0000x reference)
//
#include <hip/hip_runtime.h>

#define KEYBITS 13
#define VB (1 << KEYBITS)            // 8192 value buckets
#define SCALE 8                      // 1/8 subsample
#define RUNLEN 256                   // contiguous elements per sampled run
#define RUNSTRIDE (RUNLEN * SCALE)   // 2048

// ws layout:
//   [0, 65536)      u64  sub64[VB]   packed (pos<<32 | neg), memset 0
//   [65536, 65544)  f64  acc         memset 0
//   [66048, +32768) f32  tau[VB]     written by k_table
#define OFF_ACC 65536
#define OFF_TAB 66048
#define MEMSET_BYTES 65600

__device__ __forceinline__ unsigned err_key(float e) {
    unsigned u = __float_as_uint(e);
    return (u & 0x80000000u) ? ~u : (u | 0x80000000u);   // order-preserving
}

// ---------------------------------------------------------------------------
// K0: 1/8 subsample histogram. 8192 runs of 256 contiguous elements at
// stride 2048; one run per wave. Per-block LDS u32 packed (pos<<16|neg,
// max ~120/bucket/block); flush packs into global u64.
// ---------------------------------------------------------------------------
__global__ __launch_bounds__(1024) void k0_subhist(
    const float* __restrict__ logits, const int* __restrict__ targets,
    unsigned long long* __restrict__ g_sub, int n)
{
    __shared__ unsigned h[VB];    // 32 KB
    const int tid = threadIdx.x;
    for (int i = tid; i < VB; i += 1024) h[i] = 0u;
    __syncthreads();

    const int wave = tid >> 6, lane = tid & 63;
    const long long run = (long long)blockIdx.x * 16 + wave;
    const long long base = run * RUNSTRIDE + lane * 4;
    if (base + 3 < (long long)n) {
        const float4 L = *reinterpret_cast<const float4*>(logits + base);
        const int4  T = *reinterpret_cast<const int4*>(targets + base);
#define P0(lv, tv) {                                                   \
        float e = (tv) ? (1.0f - (lv)) : (1.0f + (lv));                \
        unsigned b = err_key(e) >> (32 - KEYBITS);                     \
        atomicAdd(&h[b], (tv) ? 0x10000u : 1u); }
        P0(L.x, T.x) P0(L.y, T.y) P0(L.z, T.z) P0(L.w, T.w)
#undef P0
    }
    __syncthreads();
    for (int i = tid; i < VB; i += 1024) {
        unsigned hv = h[i];
        if (hv)
            atomicAdd(&g_sub[i],
                      ((unsigned long long)(hv >> 16) << 32) | (hv & 0xFFFFu));
    }
}

// ---------------------------------------------------------------------------
// Kmid: single block. Suffix-scan the sub-histogram, emit per-bucket
//   tau_b = clamp( P_below_mid / max(1, n - F_mid), 0, 1 )
// with  F_mid     = SCALE*(SufC_above + c_b/2)
//       P_below_mid = SCALE*(Tp - SufP_above - p_b/2)
// No global-I dependence: numerator is the LOCAL count of positives below,
// so subsample noise stays local (no amplified correction channel).
// ---------------------------------------------------------------------------
__global__ __launch_bounds__(1024) void k_table(
    const unsigned long long* __restrict__ g_sub, float* __restrict__ g_tab,
    int n)
{
    const int t = threadIdx.x;
    __shared__ unsigned sc[1024], sp[1024];

    unsigned c[8], p[8], ct = 0, pt = 0;
    for (int k = 0; k < 8; ++k) {
        unsigned long long hv = g_sub[t * 8 + k];
        p[k] = (unsigned)(hv >> 32);
        c[k] = p[k] + (unsigned)(hv & 0xFFFFFFFFu);
        ct += c[k]; pt += p[k];
    }
    sc[t] = ct; sp[t] = pt;
    __syncthreads();
    for (int off = 1; off < 1024; off <<= 1) {    // inclusive suffix scan
        unsigned a = (t + off < 1024) ? sc[t + off] : 0u;
        unsigned b = (t + off < 1024) ? sp[t + off] : 0u;
        __syncthreads();
        sc[t] += a; sp[t] += b;
        __syncthreads();
    }

    const double dn = (double)n;
    const unsigned Tp = sp[0];                    // total sampled positives
    unsigned F = sc[t] - ct, Fp = sp[t] - pt;     // strictly-above (sampled)
    for (int k = 7; k >= 0; --k) {
        const int b = t * 8 + k;
        double Fmid   = (double)SCALE * ((double)F + 0.5 * (double)c[k]);
        double Pbelow = (double)SCALE *
                        ((double)(Tp - Fp) - 0.5 * (double)p[k]);
        double den = dn - Fmid;
        if (den < 1.0) den = 1.0;
        double tau = Pbelow / den;
        tau = tau < 0.0 ? 0.0 : (tau > 1.0 ? 1.0 : tau);
        g_tab[b] = (float)tau;
        F += c[k]; Fp += p[k];
    }
}

// ---------------------------------------------------------------------------
// K1: streaming pass, no histogram atomics. Per element: e, key,
// ds_read_b32 tau lookup, f64 accumulate of e*tau.
// ---------------------------------------------------------------------------
__global__ __launch_bounds__(1024) void k1_main(
    const float* __restrict__ logits, const int* __restrict__ targets,
    const float* __restrict__ g_tab, double* __restrict__ g_acc, int n)
{
    __shared__ float tab[VB];     // 32 KB
    __shared__ double red[16];

    const int tid = threadIdx.x;
    {   // cooperative table load (float4 = 4 entries)
        const float4* t4 = reinterpret_cast<const float4*>(g_tab);
        float4* s4 = reinterpret_cast<float4*>(tab);
        for (int i = tid; i < VB / 4; i += 1024) s4[i] = t4[i];
    }
    __syncthreads();

    double acc = 0.0;
    const long long gid = (long long)blockIdx.x * 1024 + tid;
    const long long stride = (long long)gridDim.x * 1024 * 4;

#define P1(lv, tv) {                                                   \
        float e = (tv) ? (1.0f - (lv)) : (1.0f + (lv));                \
        unsigned b = err_key(e) >> (32 - KEYBITS);                     \
        acc += (double)(e * tab[b]); }

    for (long long i = gid * 4; i + 3 < (long long)n; i += stride) {
        const float4 L = *reinterpret_cast<const float4*>(logits + i);
        const int4  T = *reinterpret_cast<const int4*>(targets + i);
        P1(L.x, T.x) P1(L.y, T.y) P1(L.z, T.z) P1(L.w, T.w)
    }
#undef P1

    for (int off = 32; off > 0; off >>= 1) acc += __shfl_xor(acc, off);
    if ((tid & 63) == 0) red[tid >> 6] = acc;
    __syncthreads();
    if (tid < 64) {
        double a = (tid < 16) ? red[tid] : 0.0;
        for (int off = 8; off > 0; off >>= 1) a += __shfl_xor(a, off);
        if (tid == 0) atomicAdd(g_acc, a);
    }
}

__global__ void k_fin(const double* __restrict__ g_acc, float* __restrict__ out)
{
    if (threadIdx.x == 0) out[0] = (float)g_acc[0];
}

extern "C" void kernel_launch(void* const* d_in, const int* in_sizes, int n_in,
                              void* d_out, int out_size, void* d_ws, size_t ws_size,
                              hipStream_t stream)
{
    const float* logits  = (const float*)d_in[0];
    const int*   targets = (const int*)d_in[1];
    const int n = in_sizes[0];

    unsigned long long* g_sub = (unsigned long long*)d_ws;
    double* g_acc = (double*)((char*)d_ws + OFF_ACC);
    float*  g_tab = (float*)((char*)d_ws + OFF_TAB);

    hipMemsetAsync(d_ws, 0, MEMSET_BYTES, stream);

    const int nruns = n / RUNSTRIDE;              // 8192 at n=2^24
    hipLaunchKernelGGL(k0_subhist, dim3((nruns + 15) / 16), dim3(1024), 0,
                       stream, logits, targets, g_sub, n);
    hipLaunchKernelGGL(k_table, dim3(1), dim3(1024), 0, stream,
                       g_sub, g_tab, n);
    hipLaunchKernelGGL(k1_main, dim3(512), dim3(1024), 0, stream,
                       logits, targets, g_tab, g_acc, n);
    hipLaunchKernelGGL(k_fin, dim3(1), dim3(64), 0, stream,
                       g_acc, (float*)d_out);
}

// Round 8
// 49.442 us; speedup vs baseline: 1.2681x; 1.2681x over previous
//
#include <hip/hip_runtime.h>

#define KEYBITS 13
#define VBUCKETS (1 << KEYBITS)          // 8192 value buckets
#define HSIZE (2 * VBUCKETS)             // class-interleaved: idx = vk*2 + cls
#define H_THREADS 1024
#define H_BLOCKS 512                     // 2 blocks/CU on 256 CUs
#define FIN_THREADS 1024
#define BPT (VBUCKETS / FIN_THREADS)     // = 8

// ws layout: g_cnt u32[HSIZE] | g_maxkey u32
#define CNT_BYTES (HSIZE * 4)

__device__ __forceinline__ unsigned err_key(float e) {
    unsigned u = __float_as_uint(e);
    return (u & 0x80000000u) ? ~u : (u | 0x80000000u);   // order-preserving
}

// ---------------------------------------------------------------------------
// K1: counts-only privatized LDS histogram, ONE ds_add_u32 per element.
// ILP x4: four independent float4+int4 pairs issued back-to-back per round
// so the loads pipeline (R7 post-mortem: 1-pair loop was latency-bound at
// ~100 cyc/elem-wave regardless of body).
// ---------------------------------------------------------------------------
__global__ __launch_bounds__(H_THREADS) void lovasz_hist(
    const float* __restrict__ logits, const int* __restrict__ targets,
    unsigned int* __restrict__ g_cnt, unsigned int* __restrict__ g_maxkey, int n)
{
    __shared__ unsigned int h[HSIZE];    // 64 KB
    __shared__ unsigned int smax;

    const int tid = threadIdx.x;
    for (int i = tid; i < HSIZE; i += H_THREADS) h[i] = 0u;
    if (tid == 0) smax = 0u;
    __syncthreads();

    unsigned int lmax = 0u;
    const long long gthreads = (long long)gridDim.x * H_THREADS;
    const long long gid = (long long)blockIdx.x * H_THREADS + tid;
    const long long S = gthreads * 4;    // elements between a thread's pairs

#define PROC(lv, tv) {                                                        \
        float e = (tv) ? (1.0f - (lv)) : (1.0f + (lv));                       \
        unsigned key = err_key(e);                                            \
        unsigned idx = ((key >> (32 - KEYBITS)) << 1) | (unsigned)((tv) != 0);\
        atomicAdd(&h[idx], 1u);                                               \
        if (key > lmax) lmax = key; }

    long long i = gid * 4;
    // main: rounds of 4 independent pairs (all 8 loads issue before use)
    while (i + 3 * S + 3 < (long long)n) {
        float4 L0 = *reinterpret_cast<const float4*>(logits + i);
        float4 L1 = *reinterpret_cast<const float4*>(logits + i + S);
        float4 L2 = *reinterpret_cast<const float4*>(logits + i + 2 * S);
        float4 L3 = *reinterpret_cast<const float4*>(logits + i + 3 * S);
        int4  T0 = *reinterpret_cast<const int4*>(targets + i);
        int4  T1 = *reinterpret_cast<const int4*>(targets + i + S);
        int4  T2 = *reinterpret_cast<const int4*>(targets + i + 2 * S);
        int4  T3 = *reinterpret_cast<const int4*>(targets + i + 3 * S);
        PROC(L0.x, T0.x) PROC(L0.y, T0.y) PROC(L0.z, T0.z) PROC(L0.w, T0.w)
        PROC(L1.x, T1.x) PROC(L1.y, T1.y) PROC(L1.z, T1.z) PROC(L1.w, T1.w)
        PROC(L2.x, T2.x) PROC(L2.y, T2.y) PROC(L2.z, T2.z) PROC(L2.w, T2.w)
        PROC(L3.x, T3.x) PROC(L3.y, T3.y) PROC(L3.z, T3.z) PROC(L3.w, T3.w)
        i += 4 * S;
    }
    // leftover whole pairs
    while (i + 3 < (long long)n) {
        float4 L = *reinterpret_cast<const float4*>(logits + i);
        int4  T = *reinterpret_cast<const int4*>(targets + i);
        PROC(L.x, T.x) PROC(L.y, T.y) PROC(L.z, T.z) PROC(L.w, T.w)
        i += S;
    }
    // scalar tail (n not multiple of 4)
    for (long long j = (long long)(n & ~3) + gid; j < (long long)n; j += gthreads) {
        float lv = logits[j]; int tv = targets[j];
        PROC(lv, tv)
    }
#undef PROC

    // wave-reduce max key, one LDS atomic per wave
    for (int off = 32; off > 0; off >>= 1) {
        unsigned o = (unsigned)__shfl_xor((int)lmax, off);
        if (o > lmax) lmax = o;
    }
    if ((tid & 63) == 0) atomicMax(&smax, lmax);
    __syncthreads();

    // flush non-empty entries (few hundred of 16384)
    for (int i2 = tid; i2 < HSIZE; i2 += H_THREADS) {
        unsigned hv = h[i2];
        if (hv) atomicAdd(&g_cnt[i2], hv);
    }
    if (tid == 0) atomicMax(g_maxkey, smax);
}

// ---------------------------------------------------------------------------
// K2: single block. Suffix scan over buckets (descending value order),
// midpoint-ratio dot over ALL buckets, grad[0] correction, scalar out.
//   c_b = cnt[2b] + cnt[2b+1], p_b = cnt[2b+1]
//   S_b = c_b * val(key_mid(b))
//   tau_b = (I - Fp - p_b/2) / (n - F - c_b/2)
//   out = sum_b S_b*tau_b - e_max * I / n
// ---------------------------------------------------------------------------
__global__ __launch_bounds__(FIN_THREADS) void lovasz_final(
    const unsigned int* __restrict__ g_cnt, const unsigned int* __restrict__ g_maxkey,
    float* __restrict__ out, int n)
{
    const int t = threadIdx.x;
    __shared__ unsigned int sc[FIN_THREADS], sp[FIN_THREADS];
    __shared__ double sd[FIN_THREADS];

    unsigned c[BPT], p[BPT];
    double sv[BPT];
    unsigned ct = 0, pt = 0;
    for (int k = 0; k < BPT; ++k) {
        const int b = t * BPT + k;
        unsigned c1 = g_cnt[2 * b + 1];
        c[k] = g_cnt[2 * b] + c1;
        p[k] = c1;
        unsigned kmid = ((unsigned)b << (32 - KEYBITS)) | (1u << (31 - KEYBITS));
        unsigned u = (kmid & 0x80000000u) ? (kmid & 0x7FFFFFFFu) : ~kmid;
        sv[k] = (double)c[k] * (double)__uint_as_float(u);
        ct += c[k]; pt += p[k];
    }
    sc[t] = ct; sp[t] = pt;
    __syncthreads();

    for (int off = 1; off < FIN_THREADS; off <<= 1) {   // inclusive suffix scan
        unsigned a = (t + off < FIN_THREADS) ? sc[t + off] : 0u;
        unsigned b = (t + off < FIN_THREADS) ? sp[t + off] : 0u;
        __syncthreads();
        sc[t] += a; sp[t] += b;
        __syncthreads();
    }

    const unsigned I = sp[0];
    const double dn = (double)n;
    const double dI = (double)I;

    unsigned F  = sc[t] - ct;
    unsigned Fp = sp[t] - pt;
    double acc = 0.0;
    for (int k = BPT - 1; k >= 0; --k) {
        if (c[k]) {
            const double tau = (dI - (double)Fp - 0.5 * (double)p[k])
                             / (dn - (double)F - 0.5 * (double)c[k]);
            acc += sv[k] * tau;
        }
        F += c[k]; Fp += p[k];
    }

    sd[t] = acc;
    __syncthreads();
    for (int off = FIN_THREADS / 2; off > 0; off >>= 1) {
        if (t < off) sd[t] += sd[t + off];
        __syncthreads();
    }

    if (t == 0) {
        unsigned mk = *g_maxkey;
        unsigned mu = (mk & 0x80000000u) ? (mk & 0x7FFFFFFFu) : ~mk;
        float emax = __uint_as_float(mu);
        out[0] = (float)(sd[0] - (double)emax * dI / dn);
    }
}

extern "C" void kernel_launch(void* const* d_in, const int* in_sizes, int n_in,
                              void* d_out, int out_size, void* d_ws, size_t ws_size,
                              hipStream_t stream)
{
    const float* logits  = (const float*)d_in[0];
    const int*   targets = (const int*)d_in[1];
    const int n = in_sizes[0];

    unsigned int* g_cnt = (unsigned int*)d_ws;
    unsigned int* g_maxkey = (unsigned int*)((char*)d_ws + CNT_BYTES);

    hipMemsetAsync(d_ws, 0, CNT_BYTES + 256, stream);

    hipLaunchKernelGGL(lovasz_hist, dim3(H_BLOCKS), dim3(H_THREADS), 0, stream,
                       logits, targets, g_cnt, g_maxkey, n);
    hipLaunchKernelGGL(lovasz_final, dim3(1), dim3(FIN_THREADS), 0, stream,
                       g_cnt, g_maxkey, (float*)d_out, n);
}

// Round 9
// 47.574 us; speedup vs baseline: 1.3179x; 1.0393x over previous
//
#include <hip/hip_runtime.h>

#define KEYBITS 13
#define VBUCKETS (1 << KEYBITS)          // 8192 value buckets
#define HSIZE (2 * VBUCKETS)             // class-interleaved: idx = vk*2 + cls
#define H_THREADS 1024
#define H_BLOCKS 512                     // 2 blocks/CU on 256 CUs
#define FIN_THREADS 1024
#define BPT (VBUCKETS / FIN_THREADS)     // = 8

// ws layout: g_cnt u32[HSIZE] | g_maxkey u32
#define CNT_BYTES (HSIZE * 4)

__device__ __forceinline__ unsigned err_key(float e) {
    unsigned u = __float_as_uint(e);
    return (u & 0x80000000u) ? ~u : (u | 0x80000000u);   // order-preserving
}

// ---------------------------------------------------------------------------
// K1: counts-only privatized LDS histogram, ONE ds_add_u32 per element.
// Software-pipelined prefetch depth 2 with sched_barrier(0) pinning the
// prefetch loads ABOVE the processing body (R8 post-mortem: without the
// pin, the scheduler sinks loads to their uses -> one pair outstanding ->
// latency-bound at ~100 cyc/elem-wave regardless of loop body).
// ---------------------------------------------------------------------------
__global__ __launch_bounds__(H_THREADS) void lovasz_hist(
    const float* __restrict__ logits, const int* __restrict__ targets,
    unsigned int* __restrict__ g_cnt, unsigned int* __restrict__ g_maxkey, int n)
{
    __shared__ unsigned int h[HSIZE];    // 64 KB
    __shared__ unsigned int smax;

    const int tid = threadIdx.x;
    for (int i = tid; i < HSIZE; i += H_THREADS) h[i] = 0u;
    if (tid == 0) smax = 0u;
    __syncthreads();

    unsigned int lmax = 0u;
    const long long gthreads = (long long)gridDim.x * H_THREADS;
    const long long gid = (long long)blockIdx.x * H_THREADS + tid;
    const long long S = gthreads * 4;    // elements between a thread's pairs

#define PROC(lv, tv) {                                                        \
        float e = (tv) ? (1.0f - (lv)) : (1.0f + (lv));                       \
        unsigned key = err_key(e);                                            \
        unsigned idx = ((key >> (32 - KEYBITS)) << 1) | (unsigned)((tv) != 0);\
        atomicAdd(&h[idx], 1u);                                               \
        if (key > lmax) lmax = key; }
#define PROC4(L, T) { PROC(L.x, T.x) PROC(L.y, T.y) PROC(L.z, T.z) PROC(L.w, T.w) }

    const bool fast = ((n & 3) == 0) && ((long long)n % S == 0)
                      && ((((long long)n / S) & 1LL) == 0LL);
    if (fast) {
        const int PAIRS = (int)((long long)n / S);   // even, >= 2
        long long i = gid * 4;
        float4 L0 = *reinterpret_cast<const float4*>(logits + i);
        int4   T0 = *reinterpret_cast<const int4*>(targets + i);
        float4 L1 = *reinterpret_cast<const float4*>(logits + i + S);
        int4   T1 = *reinterpret_cast<const int4*>(targets + i + S);
        for (int k = 0; k + 2 < PAIRS; k += 2) {
            // prefetch pairs k+2, k+3
            float4 L2 = *reinterpret_cast<const float4*>(logits + i + 2 * S);
            int4   T2 = *reinterpret_cast<const int4*>(targets + i + 2 * S);
            float4 L3 = *reinterpret_cast<const float4*>(logits + i + 3 * S);
            int4   T3 = *reinterpret_cast<const int4*>(targets + i + 3 * S);
            __builtin_amdgcn_sched_barrier(0);   // pin prefetch above body
            PROC4(L0, T0) PROC4(L1, T1)
            L0 = L2; T0 = T2; L1 = L3; T1 = T3;
            i += 2 * S;
        }
        PROC4(L0, T0) PROC4(L1, T1)
    } else {
        long long i = gid * 4;
        while (i + 3 < (long long)n) {
            float4 L = *reinterpret_cast<const float4*>(logits + i);
            int4  T = *reinterpret_cast<const int4*>(targets + i);
            PROC4(L, T)
            i += S;
        }
        for (long long j = (long long)(n & ~3) + gid; j < (long long)n; j += gthreads) {
            float lv = logits[j]; int tv = targets[j];
            PROC(lv, tv)
        }
    }
#undef PROC4
#undef PROC

    // wave-reduce max key, one LDS atomic per wave
    for (int off = 32; off > 0; off >>= 1) {
        unsigned o = (unsigned)__shfl_xor((int)lmax, off);
        if (o > lmax) lmax = o;
    }
    if ((tid & 63) == 0) atomicMax(&smax, lmax);
    __syncthreads();

    // flush non-empty entries (few hundred of 16384)
    for (int i2 = tid; i2 < HSIZE; i2 += H_THREADS) {
        unsigned hv = h[i2];
        if (hv) atomicAdd(&g_cnt[i2], hv);
    }
    if (tid == 0) atomicMax(g_maxkey, smax);
}

// ---------------------------------------------------------------------------
// K2: single block. Suffix scan over buckets (descending value order),
// midpoint-ratio dot over ALL buckets, grad[0] correction, scalar out.
//   c_b = cnt[2b] + cnt[2b+1], p_b = cnt[2b+1]
//   S_b = c_b * val(key_mid(b))
//   tau_b = (I - Fp - p_b/2) / (n - F - c_b/2)
//   out = sum_b S_b*tau_b - e_max * I / n
// ---------------------------------------------------------------------------
__global__ __launch_bounds__(FIN_THREADS) void lovasz_final(
    const unsigned int* __restrict__ g_cnt, const unsigned int* __restrict__ g_maxkey,
    float* __restrict__ out, int n)
{
    const int t = threadIdx.x;
    __shared__ unsigned int sc[FIN_THREADS], sp[FIN_THREADS];
    __shared__ double sd[FIN_THREADS];

    unsigned c[BPT], p[BPT];
    double sv[BPT];
    unsigned ct = 0, pt = 0;
    for (int k = 0; k < BPT; ++k) {
        const int b = t * BPT + k;
        unsigned c1 = g_cnt[2 * b + 1];
        c[k] = g_cnt[2 * b] + c1;
        p[k] = c1;
        unsigned kmid = ((unsigned)b << (32 - KEYBITS)) | (1u << (31 - KEYBITS));
        unsigned u = (kmid & 0x80000000u) ? (kmid & 0x7FFFFFFFu) : ~kmid;
        sv[k] = (double)c[k] * (double)__uint_as_float(u);
        ct += c[k]; pt += p[k];
    }
    sc[t] = ct; sp[t] = pt;
    __syncthreads();

    for (int off = 1; off < FIN_THREADS; off <<= 1) {   // inclusive suffix scan
        unsigned a = (t + off < FIN_THREADS) ? sc[t + off] : 0u;
        unsigned b = (t + off < FIN_THREADS) ? sp[t + off] : 0u;
        __syncthreads();
        sc[t] += a; sp[t] += b;
        __syncthreads();
    }

    const unsigned I = sp[0];
    const double dn = (double)n;
    const double dI = (double)I;

    unsigned F  = sc[t] - ct;
    unsigned Fp = sp[t] - pt;
    double acc = 0.0;
    for (int k = BPT - 1; k >= 0; --k) {
        if (c[k]) {
            const double tau = (dI - (double)Fp - 0.5 * (double)p[k])
                             / (dn - (double)F - 0.5 * (double)c[k]);
            acc += sv[k] * tau;
        }
        F += c[k]; Fp += p[k];
    }

    sd[t] = acc;
    __syncthreads();
    for (int off = FIN_THREADS / 2; off > 0; off >>= 1) {
        if (t < off) sd[t] += sd[t + off];
        __syncthreads();
    }

    if (t == 0) {
        unsigned mk = *g_maxkey;
        unsigned mu = (mk & 0x80000000u) ? (mk & 0x7FFFFFFFu) : ~mk;
        float emax = __uint_as_float(mu);
        out[0] = (float)(sd[0] - (double)emax * dI / dn);
    }
}

extern "C" void kernel_launch(void* const* d_in, const int* in_sizes, int n_in,
                              void* d_out, int out_size, void* d_ws, size_t ws_size,
                              hipStream_t stream)
{
    const float* logits  = (const float*)d_in[0];
    const int*   targets = (const int*)d_in[1];
    const int n = in_sizes[0];

    unsigned int* g_cnt = (unsigned int*)d_ws;
    unsigned int* g_maxkey = (unsigned int*)((char*)d_ws + CNT_BYTES);

    hipMemsetAsync(d_ws, 0, CNT_BYTES + 256, stream);

    hipLaunchKernelGGL(lovasz_hist, dim3(H_BLOCKS), dim3(H_THREADS), 0, stream,
                       logits, targets, g_cnt, g_maxkey, n);
    hipLaunchKernelGGL(lovasz_final, dim3(1), dim3(FIN_THREADS), 0, stream,
                       g_cnt, g_maxkey, (float*)d_out, n);
}